// Round 4
// baseline (235.847 us; speedup 1.0000x reference)
//
#include <hip/hip_runtime.h>
#include <cstdint>
#include <cstddef>

// B=2, T=4096, C=1024, H=4, G=1, hd=256, window=512, rope base 1e6, eps 1e-6.
#define T_SEQ 4096
#define NB    2
#define CDIM  1024
#define HD    256
#define NH    4

typedef __attribute__((ext_vector_type(8))) __bf16 bf16x8;
typedef __attribute__((ext_vector_type(4))) __bf16 bf16x4;
typedef __attribute__((ext_vector_type(4))) float  floatx4;

__device__ __forceinline__ floatx4 mfma16(bf16x8 a, bf16x8 b, floatx4 c) {
  return __builtin_amdgcn_mfma_f32_16x16x32_bf16(a, b, c, 0, 0, 0);
}

// async global->LDS, 16B/lane. LDS dest is wave-uniform base + lane*16 (no
// scatter) -- bank-deconflict swizzles are applied to the GLOBAL source
// address (XOR of the 16B-chunk index, stays inside one 128B segment).
__device__ __forceinline__ void gl2lds16(const void* g, void* l) {
  __builtin_amdgcn_global_load_lds(
      (__attribute__((address_space(1))) void*)g,
      (__attribute__((address_space(3))) void*)l, 16, 0, 0);
}

// ---------------------------------------------------------------- fp32 -> bf16
__global__ void cvt_f32_bf16(const float* __restrict__ in,
                             __bf16* __restrict__ out, int n4) {
  int i = blockIdx.x * 256 + threadIdx.x;
  if (i < n4) {
    float4 v = ((const float4*)in)[i];
    bf16x4 o;
    o[0] = (__bf16)v.x; o[1] = (__bf16)v.y; o[2] = (__bf16)v.z; o[3] = (__bf16)v.w;
    *(bf16x4*)&out[(size_t)i * 4] = o;
  }
}

// ------------------------------------------------- C(M,N) = A(M,K) @ B(N,K)^T
// m97 structure + XOR-swizzled LDS. M,N multiples of 128; K multiple of 64.
template <typename OutT>
__global__ __launch_bounds__(256) void gemm_bt(const __bf16* __restrict__ A,
                                               const __bf16* __restrict__ B,
                                               OutT* __restrict__ C,
                                               int M, int N, int K) {
  __shared__ __bf16 As[128 * 64];
  __shared__ __bf16 Bs[128 * 64];
  const int tid  = threadIdx.x;
  const int lane = tid & 63;
  const int wave = tid >> 6;
  const int wm = wave >> 1, wn = wave & 1;
  const int lrow = lane & 15, quad = lane >> 4;
  const int bm = blockIdx.y, bn = blockIdx.x;

  const __bf16* gA = A + (size_t)(bm * 128) * K;
  const __bf16* gB = B + (size_t)(bn * 128) * K;
  const int arow = tid >> 3;
  const int acol = ((tid & 7) ^ ((tid >> 3) & 7)) * 8;
  const int l7 = lrow & 7;

  floatx4 acc[4][4] = {};

  for (int kt = 0; kt < K; kt += 64) {
#pragma unroll
    for (int i = 0; i < 4; ++i)
      gl2lds16(gA + (size_t)(i * 32 + arow) * K + kt + acol, &As[i * 2048 + tid * 8]);
#pragma unroll
    for (int i = 0; i < 4; ++i)
      gl2lds16(gB + (size_t)(i * 32 + arow) * K + kt + acol, &Bs[i * 2048 + tid * 8]);
    __syncthreads();
#pragma unroll
    for (int kk = 0; kk < 2; ++kk) {
      bf16x8 af[4], bfr[4];
#pragma unroll
      for (int mi = 0; mi < 4; ++mi)
        af[mi] = *(const bf16x8*)&As[(wm * 64 + mi * 16 + lrow) * 64 +
                                     ((kk * 4 + quad) ^ l7) * 8];
#pragma unroll
      for (int ni = 0; ni < 4; ++ni)
        bfr[ni] = *(const bf16x8*)&Bs[(wn * 64 + ni * 16 + lrow) * 64 +
                                      ((kk * 4 + quad) ^ l7) * 8];
#pragma unroll
      for (int mi = 0; mi < 4; ++mi)
#pragma unroll
        for (int ni = 0; ni < 4; ++ni)
          acc[mi][ni] = mfma16(af[mi], bfr[ni], acc[mi][ni]);
    }
    __syncthreads();
  }

  const int row0 = bm * 128 + wm * 64;
  const int col0 = bn * 128 + wn * 64;
#pragma unroll
  for (int mi = 0; mi < 4; ++mi)
#pragma unroll
    for (int ni = 0; ni < 4; ++ni)
#pragma unroll
      for (int r = 0; r < 4; ++r) {
        int row = row0 + mi * 16 + quad * 4 + r;
        int col = col0 + ni * 16 + lrow;
        C[(size_t)row * N + col] = (OutT)acc[mi][ni][r];
      }
}

// ------------------------------------------------ RMSNorm + RoPE (+ V transpose)
__global__ __launch_bounds__(256) void rmsrope(const __bf16* __restrict__ qkv,
                                               const float* __restrict__ qg,
                                               const float* __restrict__ kg,
                                               __bf16* __restrict__ qr,
                                               __bf16* __restrict__ kr,
                                               __bf16* __restrict__ vt) {
  __shared__ __bf16 Ls[64 * 256];
  if (blockIdx.x >= 10240) {
    const int vb = blockIdx.x - 10240;     // 0..127
    const int b = vb >> 6, tt = vb & 63;
    const int tid = threadIdx.x;
    const __bf16* src = qkv + ((size_t)(b * 4096 + tt * 64)) * 1536 + 1280;
#pragma unroll
    for (int i = 0; i < 8; ++i)
      gl2lds16(src + (size_t)(i * 8 + (tid >> 5)) * 1536 + (tid & 31) * 8,
               &Ls[i * 2048 + tid * 8]);
    __syncthreads();
    __bf16 buf[64];
#pragma unroll
    for (int i = 0; i < 64; ++i) buf[i] = Ls[i * 256 + tid];
    __bf16* dst = vt + ((size_t)(b * 256 + tid)) * T_SEQ + tt * 64;
#pragma unroll
    for (int i = 0; i < 8; ++i)
      *(bf16x8*)&dst[i * 8] = *(const bf16x8*)&buf[i * 8];
    return;
  }

  const int inst = blockIdx.x * 4 + (threadIdx.x >> 6);
  const int lane = threadIdx.x & 63;
  const int row = inst / 5, which = inst - row * 5;   // row in [0, 8192)
  const int b = row >> 12, t = row & 4095;

  const int srcoff = (which < 4) ? which * 256 : 1024;
  const __bf16* src = qkv + (size_t)row * 1536 + srcoff;
  bf16x4 xv = *(const bf16x4*)&src[lane * 4];

  float x0 = (float)xv[0], x1 = (float)xv[1], x2 = (float)xv[2], x3 = (float)xv[3];
  float ss = x0 * x0 + x1 * x1 + x2 * x2 + x3 * x3;
#pragma unroll
  for (int off = 32; off >= 1; off >>= 1) ss += __shfl_xor(ss, off);
  const float rms = rsqrtf(ss * (1.0f / 256.0f) + 1e-6f);

  const float* g = (which < 4) ? qg : kg;
  const float4 gv = *(const float4*)&g[lane * 4];
  float y0 = x0 * rms * gv.x, y1 = x1 * rms * gv.y;
  float y2 = x2 * rms * gv.z, y3 = x3 * rms * gv.w;

  const float c_log2 = -19.931568569324174f / 128.0f;  // -log2(1e6)/128
  int p0 = lane * 2, p1 = lane * 2 + 1;
  float a0 = (float)t * exp2f((float)p0 * c_log2);
  float a1 = (float)t * exp2f((float)p1 * c_log2);
  float s0, c0, s1, c1;
  sincosf(a0, &s0, &c0);
  sincosf(a1, &s1, &c1);
  bf16x4 ov;
  ov[0] = (__bf16)(y0 * c0 - y1 * s0);
  ov[1] = (__bf16)(y0 * s0 + y1 * c0);
  ov[2] = (__bf16)(y2 * c1 - y3 * s1);
  ov[3] = (__bf16)(y2 * s1 + y3 * c1);

  __bf16* dst = (which < 4)
      ? qr + ((size_t)((b * NH + which) * T_SEQ) + t) * 256
      : kr + ((size_t)(b * T_SEQ) + t) * 256;
  *(bf16x4*)&dst[lane * 4] = ov;
}

// --------------------------------------------------- flash attention, window=512
// Block = (b, h, 64-query tile), grid 512 -> 2 blocks/CU. 4 waves, but split by
// KEY (QK^T) and D (PV) instead of query, so per-wave fragment reads stay at the
// 32q/wave efficiency while 16q/wave register budget keeps 2 waves/SIMD:
//   wave (wq,wk): QK^T for keys wk*32..+31 x queries wq*32..+31 (K from LDS),
//                 PV for queries wq*32..+31 x d-slice wk*128..+127 (V direct
//                 from global -- slice fits L1, reused by 2 waves).
// LDS: K tile 32KB (single-buffered; jt+1 prefetch issued after the P-barrier so
// it overlaps PV) + shared P 8KB = 40KB. 2 barriers/tile. Fixed-max softmax
// (|score|<=16): p = exp2(s*log2e/16 - 16*log2e); row-sums l via ones-MFMA.
__global__ __launch_bounds__(256, 2) void attn(const __bf16* __restrict__ qr,
                                               const __bf16* __restrict__ kr,
                                               const __bf16* __restrict__ vt,
                                               __bf16* __restrict__ ao) {
  __shared__ __bf16 Ks[64 * 256];   // [key][d], swizzled (32 KB)
  __shared__ __bf16 Ps[64 * 64];    // [query][key], swizzled (8 KB)

  const int bid = blockIdx.x;
  const int qi = bid & 63, h = (bid >> 6) & 3, b = bid >> 8;
  const int tid = threadIdx.x, wave = tid >> 6, lane = tid & 63;
  const int wq = wave & 1, wk = wave >> 1;
  const int lrow = lane & 15, quad = lane >> 4;
  const int l7 = lrow & 7;

  const __bf16* Q = qr + (size_t)((b * NH + h) * T_SEQ) * 256;
  const __bf16* K = kr + (size_t)(b * T_SEQ) * 256;
  const __bf16* V = vt + (size_t)(b * 256) * T_SEQ;

  const int qbase = qi * 64;

  // Q B-fragments (n=query=lane&15, k=quad*8+j) for this wave's 32 queries
  bf16x8 qf[2][8];
#pragma unroll
  for (int qt = 0; qt < 2; ++qt)
#pragma unroll
    for (int c = 0; c < 8; ++c)
      qf[qt][c] = *(const bf16x8*)&Q[(size_t)(qbase + wq * 32 + qt * 16 + lrow) * 256 +
                                     c * 32 + quad * 8];

  bf16x8 onesv;
#pragma unroll
  for (int j = 0; j < 8; ++j) onesv[j] = (__bf16)1.0f;

  floatx4 o[2][8] = {};   // [qt][n]: queries wq*32+qt*16.., d = wk*128+n*16..
  floatx4 lm[2] = {};

  const int jt0 = (qi >= 8) ? qi - 8 : 0;
  const int jt1 = qi;

  // stage K(jt0): rows i*8+(tid>>5), source chunk swizzled by row&7
  {
    const __bf16* Kt = K + (size_t)(jt0 * 64) * 256;
#pragma unroll
    for (int i = 0; i < 8; ++i)
      gl2lds16(Kt + (size_t)(i * 8 + (tid >> 5)) * 256 +
                   ((tid & 31) ^ ((tid >> 5) & 7)) * 8,
               &Ks[i * 2048 + tid * 8]);
  }

  for (int jt = jt0; jt <= jt1; ++jt) {
    __syncthreads();   // K(jt) staged (vmcnt drain); prior P reads done

    // S^T = K Q^T for keys wk*32..+31 x queries wq*32..+31
    floatx4 s[2][2] = {};   // [k16][qt]
#pragma unroll
    for (int c = 0; c < 8; ++c)
#pragma unroll
      for (int k16 = 0; k16 < 2; ++k16) {
        bf16x8 kf = *(const bf16x8*)&Ks[(wk * 32 + k16 * 16 + lrow) * 256 +
                                        ((c * 4 + quad) ^ l7) * 8];
#pragma unroll
        for (int qt = 0; qt < 2; ++qt)
          s[k16][qt] = mfma16(kf, qf[qt][c], s[k16][qt]);
      }

    const bool full = (jt < qi) && (jt >= qi - 7);  // interior: no masking

    // p = exp2(s*log2e/16 - 16*log2e); pack 4 keys -> ds_write_b64 into P
    const float C1 = 0.09016844005556021f;   // log2(e)/16
    const float C2 = 23.083120654223415f;    // 16*log2(e)
#pragma unroll
    for (int k16 = 0; k16 < 2; ++k16)
#pragma unroll
      for (int qt = 0; qt < 2; ++qt) {
        bf16x4 pk;
#pragma unroll
        for (int r = 0; r < 4; ++r) {
          float v = s[k16][qt][r];
          if (!full) {
            const int jk = jt * 64 + wk * 32 + k16 * 16 + quad * 4 + r;
            const int iq = qbase + wq * 32 + qt * 16 + lrow;
            v = ((jk <= iq) && (jk + 512 >= iq)) ? v : -1e30f;
          }
          pk[r] = (__bf16)exp2f(v * C1 - C2);
        }
        const int q = wq * 32 + qt * 16 + lrow;
        const int chunk = (wk * 4 + k16 * 2 + (quad >> 1)) ^ l7;
        *(bf16x4*)((char*)Ps + q * 128 + chunk * 16 + (quad & 1) * 8) = pk;
      }
    __syncthreads();   // P visible across waves; Ks reads done

    if (jt < jt1) {    // prefetch K(jt+1) -- overlaps the whole PV phase
      const __bf16* Kt = K + (size_t)((jt + 1) * 64) * 256;
#pragma unroll
      for (int i = 0; i < 8; ++i)
        gl2lds16(Kt + (size_t)(i * 8 + (tid >> 5)) * 256 +
                     ((tid & 31) ^ ((tid >> 5) & 7)) * 8,
                 &Ks[i * 2048 + tid * 8]);
    }

    // P A-fragments (m=query=lane&15, k=key=kc*32+quad*8+j)
    bf16x8 pf[2][2];
#pragma unroll
    for (int qt = 0; qt < 2; ++qt)
#pragma unroll
      for (int kc = 0; kc < 2; ++kc) {
        const int q = wq * 32 + qt * 16 + lrow;
        pf[qt][kc] = *(const bf16x8*)((char*)Ps + q * 128 +
                                      ((kc * 4 + quad) ^ l7) * 16);
      }

    // row-sums via ones-MFMA (both wk waves compute the same lm -- fine)
#pragma unroll
    for (int qt = 0; qt < 2; ++qt) {
      lm[qt] = mfma16(pf[qt][0], onesv, lm[qt]);
      lm[qt] = mfma16(pf[qt][1], onesv, lm[qt]);
    }

    // O += P V over this wave's d-slice; V read direct from global (L1/L2)
#pragma unroll
    for (int n = 0; n < 8; ++n)
#pragma unroll
      for (int kc = 0; kc < 2; ++kc) {
        bf16x8 vf = *(const bf16x8*)&V[(size_t)(wk * 128 + n * 16 + lrow) * T_SEQ +
                                       jt * 64 + kc * 32 + quad * 8];
        o[0][n] = mfma16(pf[0][kc], vf, o[0][n]);
        o[1][n] = mfma16(pf[1][kc], vf, o[1][n]);
      }
  }

  // epilogue: O/l -> ao in (B,T,H*hd) layout (A matrix of the out-projection)
#pragma unroll
  for (int qt = 0; qt < 2; ++qt)
#pragma unroll
    for (int r = 0; r < 4; ++r) {
      const float rl = 1.0f / lm[qt][r];
      const int tg = qbase + wq * 32 + qt * 16 + quad * 4 + r;
#pragma unroll
      for (int n = 0; n < 8; ++n)
        ao[((size_t)(b * T_SEQ + tg)) * CDIM + h * 256 + wk * 128 + n * 16 + lrow] =
            (__bf16)(o[qt][n][r] * rl);
    }
}

// -----------------------------------------------------------------------------
extern "C" void kernel_launch(void* const* d_in, const int* in_sizes, int n_in,
                              void* d_out, int out_size, void* d_ws, size_t ws_size,
                              hipStream_t stream) {
  const float* x  = (const float*)d_in[0];
  const float* Wq = (const float*)d_in[1];
  const float* Wk = (const float*)d_in[2];
  const float* Wv = (const float*)d_in[3];
  const float* Wo = (const float*)d_in[4];
  const float* qg = (const float*)d_in[5];
  const float* kg = (const float*)d_in[6];
  float* out = (float*)d_out;

  const size_t M = (size_t)NB * T_SEQ;  // 8192
  char* ws = (char*)d_ws;
  __bf16* xb  = (__bf16*)ws; ws += M * CDIM * 2;
  __bf16* wb  = (__bf16*)ws; ws += (size_t)1536 * CDIM * 2;
  __bf16* wob = (__bf16*)ws; ws += (size_t)CDIM * CDIM * 2;
  __bf16* qkv = (__bf16*)ws; ws += M * 1536 * 2;
  __bf16* qr  = (__bf16*)ws; ws += M * CDIM * 2;
  __bf16* kr  = (__bf16*)ws; ws += M * HD * 2;
  __bf16* vt  = (__bf16*)ws; ws += M * HD * 2;
  __bf16* ao  = (__bf16*)ws;

  cvt_f32_bf16<<<8192, 256, 0, stream>>>(x, xb, 2097152);
  cvt_f32_bf16<<<1024, 256, 0, stream>>>(Wq, wb, 262144);
  cvt_f32_bf16<<<256,  256, 0, stream>>>(Wk, wb + 1024 * 1024, 65536);
  cvt_f32_bf16<<<256,  256, 0, stream>>>(Wv, wb + 1280 * 1024, 65536);
  cvt_f32_bf16<<<1024, 256, 0, stream>>>(Wo, wob, 262144);

  // QKV projection: (8192 x 1536) = xb @ [Wq;Wk;Wv]^T
  gemm_bt<__bf16><<<dim3(12, 64), 256, 0, stream>>>(xb, wb, qkv, 8192, 1536, 1024);

  // per-head RMSNorm + RoPE on Q,K; V transpose via LDS tiles
  rmsrope<<<10368, 256, 0, stream>>>(qkv, qg, kg, qr, kr, vt);

  // sliding-window flash attention: 64-query blocks, key/d-split waves
  attn<<<NB * NH * (T_SEQ / 64), 256, 0, stream>>>(qr, kr, vt, ao);

  // output projection to fp32 d_out
  gemm_bt<float><<<dim3(8, 64), 256, 0, stream>>>(ao, wob, out, 8192, 1024, 1024);
}